// Round 5
// baseline (5179.639 us; speedup 1.0000x reference)
//
#include <hip/hip_runtime.h>

#define N_PTS 8192
#define M_PTS 2048
#define K_NN 16
#define IN_CH 64
#define G_CH 68
#define OUT_CH 128

// Unfusable fp32 ops: inline asm cannot be FMA-contracted by the compiler.
// (R4 showed __fmul_rn/__fadd_rn compile to plain ops and get contracted
// under -ffp-contract=fast: R4 output was bit-identical to R1's fmaf version.)
__device__ __forceinline__ float subrn(float a, float b) {
    float r; asm("v_sub_f32 %0, %1, %2" : "=v"(r) : "v"(a), "v"(b)); return r;
}
__device__ __forceinline__ float mulrn(float a, float b) {
    float r; asm("v_mul_f32 %0, %1, %2" : "=v"(r) : "v"(a), "v"(b)); return r;
}
__device__ __forceinline__ float addrn(float a, float b) {
    float r; asm("v_add_f32 %0, %1, %2" : "=v"(r) : "v"(a), "v"(b)); return r;
}

// numpy-exact fp32 squared distance: ((dx*dx + dy*dy) + dz*dz), per-op rounding.
__device__ __forceinline__ float sqdist_rn(float ax, float ay, float az,
                                           float bx, float by, float bz) {
    float dx = subrn(ax, bx);
    float dy = subrn(ay, by);
    float dz = subrn(az, bz);
    return addrn(addrn(mulrn(dx, dx), mulrn(dy, dy)), mulrn(dz, dz));
}

// ---------------------------------------------------------------------------
// Kernel 1: FPS, one block per batch. Bit-exact fp32 (no FMA) replication of
// the np reference chain. Tie -> smallest index (argmax first-occurrence).
// Writes down_idx and gathers down_events into d_out[0:32768].
// ---------------------------------------------------------------------------
__global__ __launch_bounds__(512) void fps_kernel(const float4* __restrict__ events4,
                                                  int* __restrict__ down_idx,
                                                  float4* __restrict__ out_de) {
    extern __shared__ char smem[];
    float* rv  = (float*)smem;                     // 8 floats
    int*   ri  = (int*)(smem + 32);                // 8 ints
    int*   ssel= (int*)(smem + 64);                // 2048 ints
    float* sx  = (float*)(smem + 64 + 4 * M_PTS);
    float* sy  = sx + N_PTS;
    float* sz  = sy + N_PTS;

    const int b = blockIdx.x;
    const int tid = threadIdx.x;
    const float4* ev = events4 + (size_t)b * N_PTS;

    for (int i = tid; i < N_PTS; i += 512) {
        float4 e = ev[i];
        sx[i] = e.x; sy[i] = e.y; sz[i] = e.z;
    }
    if (tid == 0) { ssel[0] = 0; down_idx[b * M_PTS] = 0; }
    __syncthreads();

    float px[16], py[16], pz[16], dist[16];
#pragma unroll
    for (int j = 0; j < 16; ++j) {
        int p = j * 512 + tid;
        px[j] = sx[p]; py[j] = sy[p]; pz[j] = sz[p];
        dist[j] = 1e10f;   // reference init value
    }

    int last = 0;
    const int wave = tid >> 6;
    const int lane = tid & 63;

    for (int i = 1; i < M_PTS; ++i) {
        const float lx = sx[last], ly = sy[last], lz = sz[last];
        float bd = -1.0f; int bi = 0;
#pragma unroll
        for (int j = 0; j < 16; ++j) {
            float d = sqdist_rn(px[j], py[j], pz[j], lx, ly, lz);
            d = fminf(dist[j], d);
            dist[j] = d;
            if (d > bd) { bd = d; bi = j * 512 + tid; }  // strict > => smallest idx on tie
        }
#pragma unroll
        for (int off = 1; off < 64; off <<= 1) {
            float od = __shfl_xor(bd, off);
            int   oi = __shfl_xor(bi, off);
            if (od > bd || (od == bd && oi < bi)) { bd = od; bi = oi; }
        }
        if (lane == 0) { rv[wave] = bd; ri[wave] = bi; }
        __syncthreads();
        if (tid == 0) {
            float wbd = rv[0]; int wbi = ri[0];
#pragma unroll
            for (int w = 1; w < 8; ++w) {
                float od = rv[w]; int oi = ri[w];
                if (od > wbd || (od == wbd && oi < wbi)) { wbd = od; wbi = oi; }
            }
            ssel[i] = wbi;
            down_idx[b * M_PTS + i] = wbi;
        }
        __syncthreads();
        last = ssel[i];
    }

    for (int i = tid; i < M_PTS; i += 512) {
        out_de[(size_t)b * M_PTS + i] = ev[ssel[i]];
    }
}

// ---------------------------------------------------------------------------
// Kernel 2: 16-NN per query, numpy-exact fp32 distances, lexicographic
// (d, idx) selection so boundary ties keep the smallest index (stable top_k).
// 4 threads/query over interleaved quarters, register top-16, merge in LDS.
// ---------------------------------------------------------------------------
#define KNN_REBUILD() do { float m_ = -1.0f; int mix_ = -1; int ms_ = 0;      \
    _Pragma("unroll") for (int j = 0; j < 16; ++j) {                          \
        if (nd[j] > m_ || (nd[j] == m_ && ni[j] > mix_)) {                    \
            m_ = nd[j]; mix_ = ni[j]; ms_ = j; } }                            \
    wmax = m_; widx = mix_; wslot = ms_; } while (0)

__global__ __launch_bounds__(256) void knn_kernel(const float4* __restrict__ events4,
                                                  const int* __restrict__ down_idx,
                                                  int* __restrict__ knn_idx) {
    extern __shared__ char smem[];
    float* sx = (float*)smem;
    float* sy = sx + N_PTS;
    float* sz = sy + N_PTS;
    __shared__ float md[64 * 64];
    __shared__ int   mi[64 * 64];

    const int b    = blockIdx.x >> 5;
    const int qg   = blockIdx.x & 31;
    const int tid  = threadIdx.x;
    const int ql   = tid >> 2;
    const int part = tid & 3;

    const float4* ev = events4 + (size_t)b * N_PTS;
    for (int i = tid; i < N_PTS; i += 256) {
        float4 e = ev[i];
        sx[i] = e.x; sy[i] = e.y; sz[i] = e.z;
    }
    __syncthreads();

    const int q  = qg * 64 + ql;
    const int qi = down_idx[b * M_PTS + q];
    const float qx = sx[qi], qy = sy[qi], qz = sz[qi];

    float nd[16]; int ni[16];
#pragma unroll
    for (int j = 0; j < 16; ++j) { nd[j] = 1e30f; ni[j] = 0x7fffffff; }
    float wmax = 1e30f; int widx = 0x7fffffff; int wslot = 0;

    for (int i = 0; i < N_PTS / 4; ++i) {
        const int p = i * 4 + part;
        float d = sqdist_rn(sx[p], sy[p], sz[p], qx, qy, qz);
        if (d < wmax || (d == wmax && p < widx)) {
#pragma unroll
            for (int j = 0; j < 16; ++j) if (j == wslot) { nd[j] = d; ni[j] = p; }
            KNN_REBUILD();
        }
    }
#pragma unroll
    for (int j = 0; j < 16; ++j) {
        md[ql * 64 + part * 16 + j] = nd[j];
        mi[ql * 64 + part * 16 + j] = ni[j];
    }
    __syncthreads();
    if (part == 0) {
        for (int t = 16; t < 64; ++t) {
            float d = md[ql * 64 + t];
            int   p = mi[ql * 64 + t];
            if (d < wmax || (d == wmax && p < widx)) {
#pragma unroll
                for (int j = 0; j < 16; ++j) if (j == wslot) { nd[j] = d; ni[j] = p; }
                KNN_REBUILD();
            }
        }
        int* out = knn_idx + ((size_t)(b * M_PTS + q)) * K_NN;
#pragma unroll
        for (int j = 0; j < 16; ++j) out[j] = ni[j];
    }
}

// ---------------------------------------------------------------------------
// Kernel 3: gather + per-query (16x68)@(68x128) matmul + bias; per-(b,q,d)
// max/min over k; per-channel sum/sumsq partials via atomics.
// ---------------------------------------------------------------------------
__global__ __launch_bounds__(256) void gmm_kernel(const float* __restrict__ events,
                                                  const float* __restrict__ features,
                                                  const float* __restrict__ W,
                                                  const float* __restrict__ bias,
                                                  const int* __restrict__ knn_idx,
                                                  const float* __restrict__ de,
                                                  float* __restrict__ hmax_g,
                                                  float* __restrict__ hmin_g,
                                                  float* __restrict__ gsum,
                                                  float* __restrict__ gsq) {
    __shared__ float sg[16 * G_CH];
    __shared__ float scomb[2 * OUT_CH];

    const int b   = blockIdx.x >> 7;
    const int qg  = blockIdx.x & 127;
    const int tid = threadIdx.x;
    const int d   = tid & 127;
    const int kh  = tid >> 7;

    float w[G_CH];
#pragma unroll
    for (int c = 0; c < G_CH; ++c) w[c] = W[c * OUT_CH + d];
    const float breg = bias[d];

    float ssum = 0.f, ssq = 0.f;

    for (int qq = 0; qq < 16; ++qq) {
        const int q = qg * 16 + qq;
        const int base = b * M_PTS + q;
        for (int j = tid; j < 16 * G_CH; j += 256) {
            int k = j / G_CH;
            int c = j - k * G_CH;
            int nb = knn_idx[base * K_NN + k];
            float v;
            if (c < 4) v = events[((size_t)(b * N_PTS + nb)) * 4 + c] - de[(size_t)base * 4 + c];
            else       v = features[((size_t)(b * N_PTS + nb)) * IN_CH + (c - 4)];
            sg[j] = v;
        }
        __syncthreads();

        float hmax = -1e30f, hmin = 1e30f;
#pragma unroll
        for (int k2 = 0; k2 < 8; ++k2) {
            const int k = kh * 8 + k2;
            float acc = breg;
#pragma unroll
            for (int c = 0; c < G_CH; ++c) acc = fmaf(sg[k * G_CH + c], w[c], acc);
            hmax = fmaxf(hmax, acc);
            hmin = fminf(hmin, acc);
            ssum += acc;
            ssq = fmaf(acc, acc, ssq);
        }
        if (kh == 1) { scomb[d] = hmax; scomb[OUT_CH + d] = hmin; }
        __syncthreads();
        if (kh == 0) {
            hmax = fmaxf(hmax, scomb[d]);
            hmin = fminf(hmin, scomb[OUT_CH + d]);
            hmax_g[(size_t)base * OUT_CH + d] = hmax;
            hmin_g[(size_t)base * OUT_CH + d] = hmin;
        }
        __syncthreads();
    }
    if (kh == 1) { scomb[d] = ssum; scomb[OUT_CH + d] = ssq; }
    __syncthreads();
    if (kh == 0) {
        atomicAdd(&gsum[d], ssum + scomb[d]);
        atomicAdd(&gsq[d],  ssq  + scomb[OUT_CH + d]);
    }
}

// ---------------------------------------------------------------------------
// Kernel 4: BN affine + relu + max-over-k via hmax/hmin (affine monotone).
// ---------------------------------------------------------------------------
__global__ __launch_bounds__(256) void fin_kernel(const float* __restrict__ hmax_g,
                                                  const float* __restrict__ hmin_g,
                                                  const float* __restrict__ gsum,
                                                  const float* __restrict__ gsq,
                                                  const float* __restrict__ gamma,
                                                  const float* __restrict__ beta,
                                                  float* __restrict__ out) {
    const size_t e = (size_t)blockIdx.x * 256 + threadIdx.x;
    const int d = (int)(e & 127);
    const float inv_cnt = 1.0f / 131072.0f;
    float mu  = gsum[d] * inv_cnt;
    float var = gsq[d] * inv_cnt - mu * mu;
    float a   = gamma[d] * rsqrtf(var + 1e-5f);
    float sh  = fmaf(-mu, a, beta[d]);
    float hv  = (a >= 0.f) ? hmax_g[e] : hmin_g[e];
    float r   = fmaf(a, hv, sh);
    out[32768 + e] = r > 0.f ? r : 0.f;
}

// ---------------------------------------------------------------------------
extern "C" void kernel_launch(void* const* d_in, const int* in_sizes, int n_in,
                              void* d_out, int out_size, void* d_ws, size_t ws_size,
                              hipStream_t stream) {
    const float* events   = (const float*)d_in[0];
    const float* features = (const float*)d_in[1];
    const float* W        = (const float*)d_in[2];
    const float* bias     = (const float*)d_in[3];
    const float* gamma    = (const float*)d_in[4];
    const float* beta     = (const float*)d_in[5];
    float* out = (float*)d_out;
    char* ws = (char*)d_ws;

    int*   down_idx = (int*)ws;                          // 32768 B
    int*   knn_idx  = (int*)(ws + 32768);                // 524288 B
    float* gsum     = (float*)(ws + 32768 + 524288);     // 512 B
    float* gsq      = gsum + OUT_CH;                     // 512 B
    float* hmaxg    = (float*)(ws + 558080);             // 4 MB
    float* hming    = hmaxg + (size_t)4 * M_PTS * OUT_CH;// 4 MB

    (void)hipMemsetAsync(gsum, 0, 2 * OUT_CH * sizeof(float), stream);

    const size_t fps_lds = 64 + 4 * M_PTS + (size_t)3 * N_PTS * sizeof(float);
    fps_kernel<<<4, 512, fps_lds, stream>>>((const float4*)events, down_idx, (float4*)out);

    const size_t knn_lds = (size_t)(3 * N_PTS) * sizeof(float);
    knn_kernel<<<128, 256, knn_lds, stream>>>((const float4*)events, down_idx, knn_idx);

    gmm_kernel<<<512, 256, 0, stream>>>(events, features, W, bias, knn_idx, out,
                                        hmaxg, hming, gsum, gsq);

    fin_kernel<<<4096, 256, 0, stream>>>(hmaxg, hming, gsum, gsq, gamma, beta, out);
}

// Round 6
// 3317.487 us; speedup vs baseline: 1.5613x; 1.5613x over previous
//
#include <hip/hip_runtime.h>

#define N_PTS 8192
#define M_PTS 2048
#define K_NN 16
#define IN_CH 64
#define G_CH 68
#define OUT_CH 128

// Unfusable fp32 ops: inline asm cannot be FMA-contracted by the compiler.
// (__fmul_rn/__fadd_rn get contracted under -ffp-contract=fast: R4 == R1 bitwise.)
__device__ __forceinline__ float subrn(float a, float b) {
    float r; asm("v_sub_f32 %0, %1, %2" : "=v"(r) : "v"(a), "v"(b)); return r;
}
__device__ __forceinline__ float mulrn(float a, float b) {
    float r; asm("v_mul_f32 %0, %1, %2" : "=v"(r) : "v"(a), "v"(b)); return r;
}
__device__ __forceinline__ float addrn(float a, float b) {
    float r; asm("v_add_f32 %0, %1, %2" : "=v"(r) : "v"(a), "v"(b)); return r;
}

// numpy-exact fp32 squared distance: ((dx*dx + dy*dy) + dz*dz), per-op rounding.
__device__ __forceinline__ float sqdist_rn(float ax, float ay, float az,
                                           float bx, float by, float bz) {
    float dx = subrn(ax, bx);
    float dy = subrn(ay, by);
    float dz = subrn(az, bz);
    return addrn(addrn(mulrn(dx, dx), mulrn(dy, dy)), mulrn(dz, dz));
}

// ---- DPP reduce helpers (VALU-pipe lane exchange; no DS latency) ----------
// max chain: disabled lanes get old=0 (dists are >= 0, harmless for max)
template <int CTRL, int RM>
__device__ __forceinline__ float dppmaxf(float x) {
    int r = __builtin_amdgcn_update_dpp(0, __float_as_int(x), CTRL, RM, 0xf, false);
    return fmaxf(x, __int_as_float(r));
}
// min chain: disabled lanes get old=INT_MAX
template <int CTRL, int RM>
__device__ __forceinline__ int dppmini(int x) {
    int r = __builtin_amdgcn_update_dpp(0x7fffffff, x, CTRL, RM, 0xf, false);
    return min(x, r);
}
// full 64-lane max -> valid in lane 63
__device__ __forceinline__ float wave_max64(float x) {
    x = dppmaxf<0xB1, 0xf>(x);   // quad_perm [1,0,3,2]  (xor 1)
    x = dppmaxf<0x4E, 0xf>(x);   // quad_perm [2,3,0,1]  (xor 2)
    x = dppmaxf<0x141, 0xf>(x);  // row_half_mirror      (xor 4)
    x = dppmaxf<0x140, 0xf>(x);  // row_mirror           (xor 8)
    x = dppmaxf<0x142, 0xa>(x);  // row_bcast15 -> rows 1,3
    x = dppmaxf<0x143, 0xc>(x);  // row_bcast31 -> rows 2,3; lane63 = full
    return x;
}
__device__ __forceinline__ int wave_min64(int x) {
    x = dppmini<0xB1, 0xf>(x);
    x = dppmini<0x4E, 0xf>(x);
    x = dppmini<0x141, 0xf>(x);
    x = dppmini<0x140, 0xf>(x);
    x = dppmini<0x142, 0xa>(x);
    x = dppmini<0x143, 0xc>(x);
    return x;
}
// row-of-16 reduce: every lane ends with the reduce of its 16-lane row
__device__ __forceinline__ float row16_max(float x) {
    x = dppmaxf<0xB1, 0xf>(x);
    x = dppmaxf<0x4E, 0xf>(x);
    x = dppmaxf<0x141, 0xf>(x);
    x = dppmaxf<0x140, 0xf>(x);
    return x;
}
__device__ __forceinline__ int row16_min(int x) {
    x = dppmini<0xB1, 0xf>(x);
    x = dppmini<0x4E, 0xf>(x);
    x = dppmini<0x141, 0xf>(x);
    x = dppmini<0x140, 0xf>(x);
    return x;
}

// ---------------------------------------------------------------------------
// Kernel 1: FPS, one block (1024 thr, 16 waves) per batch. Bit-exact fp32
// (no FMA) distance chain; argmax via two-phase exact reduce:
//   phase A: block max of dist (DPP wave max -> LDS 16 partials -> row16 DPP)
//   phase B: block min of index among (bd == blockmax)  (same shape, int min)
// max/min only SELECT values, so tie-break semantics match np argmax exactly.
// ---------------------------------------------------------------------------
__global__ __launch_bounds__(1024) void fps_kernel(const float4* __restrict__ events4,
                                                   int* __restrict__ down_idx,
                                                   float4* __restrict__ out_de) {
    extern __shared__ char smem[];
    float* rv  = (float*)smem;                    // 16 floats (wave max partials)
    int*   ri  = (int*)(smem + 64);               // 16 ints  (wave idx partials)
    int*   ssel= (int*)(smem + 128);              // 2048 ints
    float* sx  = (float*)(smem + 128 + 4 * M_PTS);
    float* sy  = sx + N_PTS;
    float* sz  = sy + N_PTS;

    const int b = blockIdx.x;
    const int tid = threadIdx.x;
    const float4* ev = events4 + (size_t)b * N_PTS;

    for (int i = tid; i < N_PTS; i += 1024) {
        float4 e = ev[i];
        sx[i] = e.x; sy[i] = e.y; sz[i] = e.z;
    }
    if (tid == 0) { ssel[0] = 0; down_idx[b * M_PTS] = 0; }
    __syncthreads();

    float px[8], py[8], pz[8], dist[8];
#pragma unroll
    for (int j = 0; j < 8; ++j) {
        int p = j * 1024 + tid;
        px[j] = sx[p]; py[j] = sy[p]; pz[j] = sz[p];
        dist[j] = 1e10f;   // reference init value
    }

    int last = 0;
    const int wave = tid >> 6;
    const int lane = tid & 63;

    for (int i = 1; i < M_PTS; ++i) {
        const float lx = sx[last], ly = sy[last], lz = sz[last];
        float bd = -1.0f; int bi = 0;
#pragma unroll
        for (int j = 0; j < 8; ++j) {
            float d = sqdist_rn(px[j], py[j], pz[j], lx, ly, lz);
            d = fminf(dist[j], d);
            dist[j] = d;
            if (d > bd) { bd = d; bi = j * 1024 + tid; }  // strict > => smallest p in-thread
        }
        // phase A: block max of bd
        float wm = wave_max64(bd);
        if (lane == 63) rv[wave] = wm;
        __syncthreads();
        float bm = row16_max(rv[lane & 15]);        // uniform block max
        // phase B: block min index among ties
        int cand = (bd == bm) ? bi : 0x7fffffff;
        int wmin = wave_min64(cand);
        if (lane == 63) ri[wave] = wmin;
        __syncthreads();
        int winner = row16_min(ri[lane & 15]);      // uniform winner index
        if (tid == 0) {
            ssel[i] = winner;
            down_idx[b * M_PTS + i] = winner;
        }
        last = winner;
    }
    __syncthreads();

    for (int i = tid; i < M_PTS; i += 1024) {
        out_de[(size_t)b * M_PTS + i] = ev[ssel[i]];
    }
}

// ---------------------------------------------------------------------------
// Kernel 2: 16-NN per query, numpy-exact fp32 distances, lexicographic
// (d, idx) selection (stable top_k ties). 256 blocks x 256 threads:
// 32 queries/block, 8 threads/query scanning interleaved 1024-pt partitions,
// register top-16, part-0 merge over 7x16 partials in LDS.
// ---------------------------------------------------------------------------
#define KNN_REBUILD() do { float m_ = -1.0f; int mix_ = -1; int ms_ = 0;      \
    _Pragma("unroll") for (int j = 0; j < 16; ++j) {                          \
        if (nd[j] > m_ || (nd[j] == m_ && ni[j] > mix_)) {                    \
            m_ = nd[j]; mix_ = ni[j]; ms_ = j; } }                            \
    wmax = m_; widx = mix_; wslot = ms_; } while (0)

__global__ __launch_bounds__(256) void knn_kernel(const float4* __restrict__ events4,
                                                  const int* __restrict__ down_idx,
                                                  int* __restrict__ knn_idx) {
    extern __shared__ char smem[];
    float* sx = (float*)smem;
    float* sy = sx + N_PTS;
    float* sz = sy + N_PTS;
    __shared__ float md[32 * 128];
    __shared__ int   mi[32 * 128];

    const int b    = blockIdx.x >> 6;    // 64 blocks per batch
    const int qg   = blockIdx.x & 63;    // 32 queries each
    const int tid  = threadIdx.x;
    const int ql   = tid >> 3;           // 0..31 local query
    const int part = tid & 7;            // 8 point partitions

    const float4* ev = events4 + (size_t)b * N_PTS;
    for (int i = tid; i < N_PTS; i += 256) {
        float4 e = ev[i];
        sx[i] = e.x; sy[i] = e.y; sz[i] = e.z;
    }
    __syncthreads();

    const int q  = qg * 32 + ql;
    const int qi = down_idx[b * M_PTS + q];
    const float qx = sx[qi], qy = sy[qi], qz = sz[qi];

    float nd[16]; int ni[16];
#pragma unroll
    for (int j = 0; j < 16; ++j) { nd[j] = 1e30f; ni[j] = 0x7fffffff; }
    float wmax = 1e30f; int widx = 0x7fffffff; int wslot = 0;

    for (int i = 0; i < N_PTS / 8; ++i) {
        const int p = i * 8 + part;
        float d = sqdist_rn(sx[p], sy[p], sz[p], qx, qy, qz);
        if (d < wmax || (d == wmax && p < widx)) {
#pragma unroll
            for (int j = 0; j < 16; ++j) if (j == wslot) { nd[j] = d; ni[j] = p; }
            KNN_REBUILD();
        }
    }
#pragma unroll
    for (int j = 0; j < 16; ++j) {
        md[ql * 128 + part * 16 + j] = nd[j];
        mi[ql * 128 + part * 16 + j] = ni[j];
    }
    __syncthreads();
    if (part == 0) {
        for (int t = 16; t < 128; ++t) {
            float d = md[ql * 128 + t];
            int   p = mi[ql * 128 + t];
            if (d < wmax || (d == wmax && p < widx)) {
#pragma unroll
                for (int j = 0; j < 16; ++j) if (j == wslot) { nd[j] = d; ni[j] = p; }
                KNN_REBUILD();
            }
        }
        int* out = knn_idx + ((size_t)(b * M_PTS + q)) * K_NN;
#pragma unroll
        for (int j = 0; j < 16; ++j) out[j] = ni[j];
    }
}

// ---------------------------------------------------------------------------
// Kernel 3: gather + per-query (16x68)@(68x128) matmul + bias; per-(b,q,d)
// max/min over k; per-channel sum/sumsq partials via atomics.
// ---------------------------------------------------------------------------
__global__ __launch_bounds__(256) void gmm_kernel(const float* __restrict__ events,
                                                  const float* __restrict__ features,
                                                  const float* __restrict__ W,
                                                  const float* __restrict__ bias,
                                                  const int* __restrict__ knn_idx,
                                                  const float* __restrict__ de,
                                                  float* __restrict__ hmax_g,
                                                  float* __restrict__ hmin_g,
                                                  float* __restrict__ gsum,
                                                  float* __restrict__ gsq) {
    __shared__ float sg[16 * G_CH];
    __shared__ float scomb[2 * OUT_CH];

    const int b   = blockIdx.x >> 7;
    const int qg  = blockIdx.x & 127;
    const int tid = threadIdx.x;
    const int d   = tid & 127;
    const int kh  = tid >> 7;

    float w[G_CH];
#pragma unroll
    for (int c = 0; c < G_CH; ++c) w[c] = W[c * OUT_CH + d];
    const float breg = bias[d];

    float ssum = 0.f, ssq = 0.f;

    for (int qq = 0; qq < 16; ++qq) {
        const int q = qg * 16 + qq;
        const int base = b * M_PTS + q;
        for (int j = tid; j < 16 * G_CH; j += 256) {
            int k = j / G_CH;
            int c = j - k * G_CH;
            int nb = knn_idx[base * K_NN + k];
            float v;
            if (c < 4) v = events[((size_t)(b * N_PTS + nb)) * 4 + c] - de[(size_t)base * 4 + c];
            else       v = features[((size_t)(b * N_PTS + nb)) * IN_CH + (c - 4)];
            sg[j] = v;
        }
        __syncthreads();

        float hmax = -1e30f, hmin = 1e30f;
#pragma unroll
        for (int k2 = 0; k2 < 8; ++k2) {
            const int k = kh * 8 + k2;
            float acc = breg;
#pragma unroll
            for (int c = 0; c < G_CH; ++c) acc = fmaf(sg[k * G_CH + c], w[c], acc);
            hmax = fmaxf(hmax, acc);
            hmin = fminf(hmin, acc);
            ssum += acc;
            ssq = fmaf(acc, acc, ssq);
        }
        if (kh == 1) { scomb[d] = hmax; scomb[OUT_CH + d] = hmin; }
        __syncthreads();
        if (kh == 0) {
            hmax = fmaxf(hmax, scomb[d]);
            hmin = fminf(hmin, scomb[OUT_CH + d]);
            hmax_g[(size_t)base * OUT_CH + d] = hmax;
            hmin_g[(size_t)base * OUT_CH + d] = hmin;
        }
        __syncthreads();
    }
    if (kh == 1) { scomb[d] = ssum; scomb[OUT_CH + d] = ssq; }
    __syncthreads();
    if (kh == 0) {
        atomicAdd(&gsum[d], ssum + scomb[d]);
        atomicAdd(&gsq[d],  ssq  + scomb[OUT_CH + d]);
    }
}

// ---------------------------------------------------------------------------
// Kernel 4: BN affine + relu + max-over-k via hmax/hmin (affine monotone).
// ---------------------------------------------------------------------------
__global__ __launch_bounds__(256) void fin_kernel(const float* __restrict__ hmax_g,
                                                  const float* __restrict__ hmin_g,
                                                  const float* __restrict__ gsum,
                                                  const float* __restrict__ gsq,
                                                  const float* __restrict__ gamma,
                                                  const float* __restrict__ beta,
                                                  float* __restrict__ out) {
    const size_t e = (size_t)blockIdx.x * 256 + threadIdx.x;
    const int d = (int)(e & 127);
    const float inv_cnt = 1.0f / 131072.0f;
    float mu  = gsum[d] * inv_cnt;
    float var = gsq[d] * inv_cnt - mu * mu;
    float a   = gamma[d] * rsqrtf(var + 1e-5f);
    float sh  = fmaf(-mu, a, beta[d]);
    float hv  = (a >= 0.f) ? hmax_g[e] : hmin_g[e];
    float r   = fmaf(a, hv, sh);
    out[32768 + e] = r > 0.f ? r : 0.f;
}

// ---------------------------------------------------------------------------
extern "C" void kernel_launch(void* const* d_in, const int* in_sizes, int n_in,
                              void* d_out, int out_size, void* d_ws, size_t ws_size,
                              hipStream_t stream) {
    const float* events   = (const float*)d_in[0];
    const float* features = (const float*)d_in[1];
    const float* W        = (const float*)d_in[2];
    const float* bias     = (const float*)d_in[3];
    const float* gamma    = (const float*)d_in[4];
    const float* beta     = (const float*)d_in[5];
    float* out = (float*)d_out;
    char* ws = (char*)d_ws;

    int*   down_idx = (int*)ws;                          // 32768 B
    int*   knn_idx  = (int*)(ws + 32768);                // 524288 B
    float* gsum     = (float*)(ws + 32768 + 524288);     // 512 B
    float* gsq      = gsum + OUT_CH;                     // 512 B
    float* hmaxg    = (float*)(ws + 558080);             // 4 MB
    float* hming    = hmaxg + (size_t)4 * M_PTS * OUT_CH;// 4 MB

    (void)hipMemsetAsync(gsum, 0, 2 * OUT_CH * sizeof(float), stream);

    const size_t fps_lds = 128 + 4 * M_PTS + (size_t)3 * N_PTS * sizeof(float);
    fps_kernel<<<4, 1024, fps_lds, stream>>>((const float4*)events, down_idx, (float4*)out);

    const size_t knn_lds = (size_t)(3 * N_PTS) * sizeof(float);
    knn_kernel<<<256, 256, knn_lds, stream>>>((const float4*)events, down_idx, knn_idx);

    gmm_kernel<<<512, 256, 0, stream>>>(events, features, W, bias, knn_idx, out,
                                        hmaxg, hming, gsum, gsq);

    fin_kernel<<<4096, 256, 0, stream>>>(hmaxg, hming, gsum, gsq, gamma, beta, out);
}

// Round 7
// 2730.429 us; speedup vs baseline: 1.8970x; 1.2150x over previous
//
#include <hip/hip_runtime.h>

#define N_PTS 8192
#define M_PTS 2048
#define K_NN 16
#define IN_CH 64
#define G_CH 68
#define OUT_CH 128
#define KCAP 128

// Unfusable fp32 ops: inline asm cannot be FMA-contracted by the compiler.
__device__ __forceinline__ float subrn(float a, float b) {
    float r; asm("v_sub_f32 %0, %1, %2" : "=v"(r) : "v"(a), "v"(b)); return r;
}
__device__ __forceinline__ float mulrn(float a, float b) {
    float r; asm("v_mul_f32 %0, %1, %2" : "=v"(r) : "v"(a), "v"(b)); return r;
}
__device__ __forceinline__ float addrn(float a, float b) {
    float r; asm("v_add_f32 %0, %1, %2" : "=v"(r) : "v"(a), "v"(b)); return r;
}
// numpy-exact fp32 squared distance: ((dx*dx + dy*dy) + dz*dz), per-op rounding.
__device__ __forceinline__ float sqdist_rn(float ax, float ay, float az,
                                           float bx, float by, float bz) {
    float dx = subrn(ax, bx);
    float dy = subrn(ay, by);
    float dz = subrn(az, bz);
    return addrn(addrn(mulrn(dx, dx), mulrn(dy, dy)), mulrn(dz, dz));
}

// Packed 2xfp32 ops (VOP3P, gfx90a+). Each half is a plain IEEE fp32 op, so
// numerics are bit-identical to the scalar versions. Subtraction is done as
// a + (-b) (exact: fp32 negation is a sign flip; a+(-b) rounds same as a-b).
typedef float v2f __attribute__((ext_vector_type(2)));
__device__ __forceinline__ v2f pk_add(v2f a, v2f b) {
    v2f r; asm("v_pk_add_f32 %0, %1, %2" : "=v"(r) : "v"(a), "v"(b)); return r;
}
__device__ __forceinline__ v2f pk_mul(v2f a, v2f b) {
    v2f r; asm("v_pk_mul_f32 %0, %1, %2" : "=v"(r) : "v"(a), "v"(b)); return r;
}

// ---- DPP reduce helpers (VALU-pipe lane exchange) -------------------------
template <int CTRL, int RM>
__device__ __forceinline__ float dppmaxf(float x) {
    int r = __builtin_amdgcn_update_dpp(0, __float_as_int(x), CTRL, RM, 0xf, false);
    return fmaxf(x, __int_as_float(r));
}
template <int CTRL, int RM>
__device__ __forceinline__ int dppmini(int x) {
    int r = __builtin_amdgcn_update_dpp(0x7fffffff, x, CTRL, RM, 0xf, false);
    return min(x, r);
}
__device__ __forceinline__ float wave_max64(float x) {
    x = dppmaxf<0xB1, 0xf>(x);   // xor 1
    x = dppmaxf<0x4E, 0xf>(x);   // xor 2
    x = dppmaxf<0x141, 0xf>(x);  // half-row mirror (xor 7 -> covers bit 2)
    x = dppmaxf<0x140, 0xf>(x);  // row mirror
    x = dppmaxf<0x142, 0xa>(x);  // row_bcast15
    x = dppmaxf<0x143, 0xc>(x);  // row_bcast31; lane63 = full wave
    return x;
}
__device__ __forceinline__ int wave_min64(int x) {
    x = dppmini<0xB1, 0xf>(x);
    x = dppmini<0x4E, 0xf>(x);
    x = dppmini<0x141, 0xf>(x);
    x = dppmini<0x140, 0xf>(x);
    x = dppmini<0x142, 0xa>(x);
    x = dppmini<0x143, 0xc>(x);
    return x;
}
__device__ __forceinline__ float row16_max(float x) {
    x = dppmaxf<0xB1, 0xf>(x);
    x = dppmaxf<0x4E, 0xf>(x);
    x = dppmaxf<0x141, 0xf>(x);
    x = dppmaxf<0x140, 0xf>(x);
    return x;
}
__device__ __forceinline__ int row16_min(int x) {
    x = dppmini<0xB1, 0xf>(x);
    x = dppmini<0x4E, 0xf>(x);
    x = dppmini<0x141, 0xf>(x);
    x = dppmini<0x140, 0xf>(x);
    return x;
}
// 8-lane-group max (groups aligned to lane%8): xor1, xor2, then half-row mirror
__device__ __forceinline__ float group8_max(float x) {
    x = dppmaxf<0xB1, 0xf>(x);
    x = dppmaxf<0x4E, 0xf>(x);
    x = dppmaxf<0x141, 0xf>(x);
    return x;
}

// ---------------------------------------------------------------------------
// Kernel 1: FPS, one block (1024 thr) per batch. Bit-exact fp32 (no FMA)
// distance chain, pk-packed 2 points/instr. Argmax: in-loop fmax only;
// in-thread index resolved post-loop (descending cndmask -> smallest index);
// block reduce = 2-phase DPP (max dist, then min index among ties).
// ---------------------------------------------------------------------------
__global__ __launch_bounds__(1024) void fps_kernel(const float4* __restrict__ events4,
                                                   int* __restrict__ down_idx,
                                                   float4* __restrict__ out_de) {
    extern __shared__ char smem[];
    float*  rv  = (float*)smem;                    // 16 floats
    int*    ri  = (int*)(smem + 64);               // 16 ints
    int*    ssel= (int*)(smem + 128);              // 2048 ints
    float4* spt = (float4*)(smem + 128 + 4 * M_PTS); // 8192 float4 (131072 B)

    const int b = blockIdx.x;
    const int tid = threadIdx.x;
    const float4* ev = events4 + (size_t)b * N_PTS;

    for (int i = tid; i < N_PTS; i += 1024) spt[i] = ev[i];
    if (tid == 0) { ssel[0] = 0; down_idx[b * M_PTS] = 0; }
    __syncthreads();

    // 8 points per thread, packed in pairs: pair pp holds pts (2pp)*1024+tid, (2pp+1)*1024+tid
    v2f px[4], py[4], pz[4];
    float dist[8];
#pragma unroll
    for (int pp = 0; pp < 4; ++pp) {
        float4 f0 = spt[(2 * pp) * 1024 + tid];
        float4 f1 = spt[(2 * pp + 1) * 1024 + tid];
        px[pp] = (v2f){f0.x, f1.x};
        py[pp] = (v2f){f0.y, f1.y};
        pz[pp] = (v2f){f0.z, f1.z};
        dist[2 * pp] = 1e10f; dist[2 * pp + 1] = 1e10f;  // reference init
    }

    int last = 0;
    const int wave = tid >> 6;
    const int lane = tid & 63;

    for (int i = 1; i < M_PTS; ++i) {
        float4 L = spt[last];                 // 1 ds_read_b128 broadcast
        const float nlx = -L.x, nly = -L.y, nlz = -L.z;   // exact sign flips
        const v2f nx2 = (v2f){nlx, nlx};
        const v2f ny2 = (v2f){nly, nly};
        const v2f nz2 = (v2f){nlz, nlz};
        float bd = -1.0f;
#pragma unroll
        for (int pp = 0; pp < 4; ++pp) {
            v2f dx = pk_add(px[pp], nx2);     // == px - lx, exact
            v2f dy = pk_add(py[pp], ny2);
            v2f dz = pk_add(pz[pp], nz2);
            v2f s  = pk_add(pk_add(pk_mul(dx, dx), pk_mul(dy, dy)), pk_mul(dz, dz));
            float d0 = fminf(dist[2 * pp],     s.x);
            float d1 = fminf(dist[2 * pp + 1], s.y);
            dist[2 * pp] = d0; dist[2 * pp + 1] = d1;
            bd = fmaxf(bd, d0); bd = fmaxf(bd, d1);
        }
        // in-thread index: smallest j with dist[j]==bd (descending overwrite)
        int bi = 0;
#pragma unroll
        for (int j = 7; j >= 0; --j) if (dist[j] == bd) bi = j * 1024 + tid;

        // phase A: block max of bd
        float wm = wave_max64(bd);
        if (lane == 63) rv[wave] = wm;
        __syncthreads();
        float bm = row16_max(rv[lane & 15]);
        // phase B: block min index among exact ties
        int cand = (bd == bm) ? bi : 0x7fffffff;
        int wmin = wave_min64(cand);
        if (lane == 63) ri[wave] = wmin;
        __syncthreads();
        int winner = row16_min(ri[lane & 15]);
        if (tid == 0) {
            ssel[i] = winner;
            down_idx[b * M_PTS + i] = winner;
        }
        last = winner;
    }
    __syncthreads();

    for (int i = tid; i < M_PTS; i += 1024) {
        out_de[(size_t)b * M_PTS + i] = spt[ssel[i]];
    }
}

// ---------------------------------------------------------------------------
// Kernel 2: 16-NN, divergence-free threshold algorithm.
//  pass1: per lane (8 lanes/query, 1024 pts each) branchless top-2 smallest.
//         T = group8_max(m2) >= true 16th distance (union of per-lane top-2
//         is 16 points all <= T).
//  pass2: compact candidates with d <= T into LDS (expected ~16-60/query).
//  pass3: one lane/query does exact stable (d, idx)-lexicographic top-16.
//  Overflow (>KCAP candidates, ~impossible) -> exact serial fallback.
// ---------------------------------------------------------------------------
__global__ __launch_bounds__(256) void knn_kernel(const float4* __restrict__ events4,
                                                  const int* __restrict__ down_idx,
                                                  int* __restrict__ knn_idx) {
    extern __shared__ char smem[];
    float* sx   = (float*)smem;                  // 8192
    float* sy   = sx + N_PTS;
    float* sz   = sy + N_PTS;
    float* cd   = sz + N_PTS;                    // 32*KCAP floats
    int*   ci   = (int*)(cd + 32 * KCAP);        // 32*KCAP ints
    int*   scnt = (int*)(ci + 32 * KCAP);        // 32 ints

    const int b    = blockIdx.x >> 6;    // 64 blocks per batch
    const int qg   = blockIdx.x & 63;    // 32 queries each
    const int tid  = threadIdx.x;
    const int ql   = tid >> 3;           // 0..31 local query
    const int part = tid & 7;            // 8 point partitions

    const float4* ev = events4 + (size_t)b * N_PTS;
    for (int i = tid; i < N_PTS; i += 256) {
        float4 e = ev[i];
        sx[i] = e.x; sy[i] = e.y; sz[i] = e.z;
    }
    if (tid < 32) scnt[tid] = 0;
    __syncthreads();

    const int q  = qg * 32 + ql;
    const int qi = down_idx[b * M_PTS + q];
    const float qx = sx[qi], qy = sy[qi], qz = sz[qi];

    // pass 1: branchless top-2 smallest per lane
    float m1 = 1e30f, m2 = 1e30f;
    for (int i = 0; i < N_PTS / 8; ++i) {
        const int p = i * 8 + part;
        float d = sqdist_rn(sx[p], sy[p], sz[p], qx, qy, qz);
        float lo = fminf(m1, d);
        m2 = fminf(m2, fmaxf(m1, d));
        m1 = lo;
    }
    const float T = group8_max(m2);   // uniform across the 8 lanes of this query

    // pass 2: compact candidates
    for (int i = 0; i < N_PTS / 8; ++i) {
        const int p = i * 8 + part;
        float d = sqdist_rn(sx[p], sy[p], sz[p], qx, qy, qz);
        if (d <= T) {
            int pos = atomicAdd(&scnt[ql], 1);
            if (pos < KCAP) { cd[ql * KCAP + pos] = d; ci[ql * KCAP + pos] = p; }
        }
    }
    __syncthreads();

    // pass 3: exact stable top-16 (lexicographic (d, idx))
    if (part == 0) {
        float nd[16]; int ni[16];
#pragma unroll
        for (int j = 0; j < 16; ++j) { nd[j] = 1e30f; ni[j] = 0x7fffffff; }
        float wmax = 1e30f; int widx = 0x7fffffff; int wslot = 0;
        const int n = scnt[ql];
        const int lim = (n <= KCAP) ? n : 0;   // overflow -> skip, use fallback
        for (int t = 0; t < lim; ++t) {
            float d = cd[ql * KCAP + t];
            int   p = ci[ql * KCAP + t];
            if (d < wmax || (d == wmax && p < widx)) {
#pragma unroll
                for (int j = 0; j < 16; ++j) if (j == wslot) { nd[j] = d; ni[j] = p; }
                float m_ = -1.0f; int mix_ = -1; int ms_ = 0;
#pragma unroll
                for (int j = 0; j < 16; ++j)
                    if (nd[j] > m_ || (nd[j] == m_ && ni[j] > mix_)) { m_ = nd[j]; mix_ = ni[j]; ms_ = j; }
                wmax = m_; widx = mix_; wslot = ms_;
            }
        }
        if (n > KCAP) {   // exact serial fallback (never expected)
            for (int p = 0; p < N_PTS; ++p) {
                float d = sqdist_rn(sx[p], sy[p], sz[p], qx, qy, qz);
                if (d < wmax || (d == wmax && p < widx)) {
#pragma unroll
                    for (int j = 0; j < 16; ++j) if (j == wslot) { nd[j] = d; ni[j] = p; }
                    float m_ = -1.0f; int mix_ = -1; int ms_ = 0;
#pragma unroll
                    for (int j = 0; j < 16; ++j)
                        if (nd[j] > m_ || (nd[j] == m_ && ni[j] > mix_)) { m_ = nd[j]; mix_ = ni[j]; ms_ = j; }
                    wmax = m_; widx = mix_; wslot = ms_;
                }
            }
        }
        int* out = knn_idx + ((size_t)(b * M_PTS + q)) * K_NN;
#pragma unroll
        for (int j = 0; j < 16; ++j) out[j] = ni[j];
    }
}

// ---------------------------------------------------------------------------
// Kernel 3: gather + per-query (16x68)@(68x128) matmul + bias; per-(b,q,d)
// max/min over k; per-channel sum/sumsq via atomics. sg read as float4
// (ds_read_b128, 17/k-row) to relieve the LDS pipe.
// ---------------------------------------------------------------------------
__global__ __launch_bounds__(256) void gmm_kernel(const float* __restrict__ events,
                                                  const float* __restrict__ features,
                                                  const float* __restrict__ W,
                                                  const float* __restrict__ bias,
                                                  const int* __restrict__ knn_idx,
                                                  const float* __restrict__ de,
                                                  float* __restrict__ hmax_g,
                                                  float* __restrict__ hmin_g,
                                                  float* __restrict__ gsum,
                                                  float* __restrict__ gsq) {
    __shared__ __align__(16) float sg[16 * G_CH];
    __shared__ float scomb[2 * OUT_CH];

    const int b   = blockIdx.x >> 7;
    const int qg  = blockIdx.x & 127;
    const int tid = threadIdx.x;
    const int d   = tid & 127;
    const int kh  = tid >> 7;

    float w[G_CH];
#pragma unroll
    for (int c = 0; c < G_CH; ++c) w[c] = W[c * OUT_CH + d];
    const float breg = bias[d];

    float ssum = 0.f, ssq = 0.f;
    const float4* sg4 = (const float4*)sg;

    for (int qq = 0; qq < 16; ++qq) {
        const int q = qg * 16 + qq;
        const int base = b * M_PTS + q;
        for (int j = tid; j < 16 * G_CH; j += 256) {
            int k = j / G_CH;
            int c = j - k * G_CH;
            int nb = knn_idx[base * K_NN + k];
            float v;
            if (c < 4) v = events[((size_t)(b * N_PTS + nb)) * 4 + c] - de[(size_t)base * 4 + c];
            else       v = features[((size_t)(b * N_PTS + nb)) * IN_CH + (c - 4)];
            sg[j] = v;
        }
        __syncthreads();

        float hmax = -1e30f, hmin = 1e30f;
#pragma unroll
        for (int k2 = 0; k2 < 8; ++k2) {
            const int k = kh * 8 + k2;
            float acc = breg;
#pragma unroll
            for (int c4 = 0; c4 < 17; ++c4) {
                float4 g = sg4[k * 17 + c4];
                acc = fmaf(g.x, w[4 * c4 + 0], acc);
                acc = fmaf(g.y, w[4 * c4 + 1], acc);
                acc = fmaf(g.z, w[4 * c4 + 2], acc);
                acc = fmaf(g.w, w[4 * c4 + 3], acc);
            }
            hmax = fmaxf(hmax, acc);
            hmin = fminf(hmin, acc);
            ssum += acc;
            ssq = fmaf(acc, acc, ssq);
        }
        if (kh == 1) { scomb[d] = hmax; scomb[OUT_CH + d] = hmin; }
        __syncthreads();
        if (kh == 0) {
            hmax = fmaxf(hmax, scomb[d]);
            hmin = fminf(hmin, scomb[OUT_CH + d]);
            hmax_g[(size_t)base * OUT_CH + d] = hmax;
            hmin_g[(size_t)base * OUT_CH + d] = hmin;
        }
        __syncthreads();
    }
    if (kh == 1) { scomb[d] = ssum; scomb[OUT_CH + d] = ssq; }
    __syncthreads();
    if (kh == 0) {
        atomicAdd(&gsum[d], ssum + scomb[d]);
        atomicAdd(&gsq[d],  ssq  + scomb[OUT_CH + d]);
    }
}

// ---------------------------------------------------------------------------
// Kernel 4: BN affine + relu + max-over-k via hmax/hmin (affine monotone).
// ---------------------------------------------------------------------------
__global__ __launch_bounds__(256) void fin_kernel(const float* __restrict__ hmax_g,
                                                  const float* __restrict__ hmin_g,
                                                  const float* __restrict__ gsum,
                                                  const float* __restrict__ gsq,
                                                  const float* __restrict__ gamma,
                                                  const float* __restrict__ beta,
                                                  float* __restrict__ out) {
    const size_t e = (size_t)blockIdx.x * 256 + threadIdx.x;
    const int d = (int)(e & 127);
    const float inv_cnt = 1.0f / 131072.0f;
    float mu  = gsum[d] * inv_cnt;
    float var = gsq[d] * inv_cnt - mu * mu;
    float a   = gamma[d] * rsqrtf(var + 1e-5f);
    float sh  = fmaf(-mu, a, beta[d]);
    float hv  = (a >= 0.f) ? hmax_g[e] : hmin_g[e];
    float r   = fmaf(a, hv, sh);
    out[32768 + e] = r > 0.f ? r : 0.f;
}

// ---------------------------------------------------------------------------
extern "C" void kernel_launch(void* const* d_in, const int* in_sizes, int n_in,
                              void* d_out, int out_size, void* d_ws, size_t ws_size,
                              hipStream_t stream) {
    const float* events   = (const float*)d_in[0];
    const float* features = (const float*)d_in[1];
    const float* W        = (const float*)d_in[2];
    const float* bias     = (const float*)d_in[3];
    const float* gamma    = (const float*)d_in[4];
    const float* beta     = (const float*)d_in[5];
    float* out = (float*)d_out;
    char* ws = (char*)d_ws;

    int*   down_idx = (int*)ws;                          // 32768 B
    int*   knn_idx  = (int*)(ws + 32768);                // 524288 B
    float* gsum     = (float*)(ws + 32768 + 524288);     // 512 B
    float* gsq      = gsum + OUT_CH;                     // 512 B
    float* hmaxg    = (float*)(ws + 558080);             // 4 MB
    float* hming    = hmaxg + (size_t)4 * M_PTS * OUT_CH;// 4 MB

    (void)hipMemsetAsync(gsum, 0, 2 * OUT_CH * sizeof(float), stream);

    const size_t fps_lds = 128 + 4 * M_PTS + (size_t)N_PTS * sizeof(float4); // 139392
    fps_kernel<<<4, 1024, fps_lds, stream>>>((const float4*)events, down_idx, (float4*)out);

    const size_t knn_lds = (size_t)3 * N_PTS * sizeof(float)
                         + (size_t)32 * KCAP * 8 + 128;                      // 131200
    knn_kernel<<<256, 256, knn_lds, stream>>>((const float4*)events, down_idx, knn_idx);

    gmm_kernel<<<512, 256, 0, stream>>>(events, features, W, bias, knn_idx, out,
                                        hmaxg, hming, gsum, gsq);

    fin_kernel<<<4096, 256, 0, stream>>>(hmaxg, hming, gsum, gsq, gamma, beta, out);
}

// Round 8
// 2442.544 us; speedup vs baseline: 2.1206x; 1.1179x over previous
//
#include <hip/hip_runtime.h>

#define N_PTS 8192
#define M_PTS 2048
#define K_NN 16
#define IN_CH 64
#define G_CH 68
#define OUT_CH 128
#define KCAP 128

// Unfusable fp32 ops: inline asm cannot be FMA-contracted by the compiler.
__device__ __forceinline__ float subrn(float a, float b) {
    float r; asm("v_sub_f32 %0, %1, %2" : "=v"(r) : "v"(a), "v"(b)); return r;
}
__device__ __forceinline__ float mulrn(float a, float b) {
    float r; asm("v_mul_f32 %0, %1, %2" : "=v"(r) : "v"(a), "v"(b)); return r;
}
__device__ __forceinline__ float addrn(float a, float b) {
    float r; asm("v_add_f32 %0, %1, %2" : "=v"(r) : "v"(a), "v"(b)); return r;
}
// numpy-exact fp32 squared distance: ((dx*dx + dy*dy) + dz*dz), per-op rounding.
__device__ __forceinline__ float sqdist_rn(float ax, float ay, float az,
                                           float bx, float by, float bz) {
    float dx = subrn(ax, bx);
    float dy = subrn(ay, by);
    float dz = subrn(az, bz);
    return addrn(addrn(mulrn(dx, dx), mulrn(dy, dy)), mulrn(dz, dz));
}

// Packed 2xfp32 ops (VOP3P). Each half is a plain IEEE fp32 op -> numerics
// bit-identical to scalar. Subtraction as a + (-b) (exact sign flip).
typedef float v2f __attribute__((ext_vector_type(2)));
__device__ __forceinline__ v2f pk_add(v2f a, v2f b) {
    v2f r; asm("v_pk_add_f32 %0, %1, %2" : "=v"(r) : "v"(a), "v"(b)); return r;
}
__device__ __forceinline__ v2f pk_mul(v2f a, v2f b) {
    v2f r; asm("v_pk_mul_f32 %0, %1, %2" : "=v"(r) : "v"(a), "v"(b)); return r;
}

// ---- DPP helpers ----------------------------------------------------------
// mov_dpp: 1 instr/stage; safe when all source lanes valid (xor1/2, mirrors).
template <int CTRL>
__device__ __forceinline__ float movdpp_f(float x) {
    int r = __builtin_amdgcn_mov_dpp(__float_as_int(x), CTRL, 0xf, 0xf, true);
    return __int_as_float(r);
}
template <int CTRL>
__device__ __forceinline__ int movdpp_i(int x) {
    return __builtin_amdgcn_mov_dpp(x, CTRL, 0xf, 0xf, true);
}
// masked bcast stages for wave max: update_dpp old=0 (max with 0 safe, d>=0)
template <int CTRL, int RM>
__device__ __forceinline__ float dppmaxf_m(float x) {
    int r = __builtin_amdgcn_update_dpp(0, __float_as_int(x), CTRL, RM, 0xf, false);
    return fmaxf(x, __int_as_float(r));
}
// full 64-lane max -> valid in lane 63
__device__ __forceinline__ float wave_max64(float x) {
    x = fmaxf(x, movdpp_f<0xB1>(x));   // quad_perm xor1
    x = fmaxf(x, movdpp_f<0x4E>(x));   // quad_perm xor2
    x = fmaxf(x, movdpp_f<0x141>(x));  // row_half_mirror
    x = fmaxf(x, movdpp_f<0x140>(x));  // row_mirror
    x = dppmaxf_m<0x142, 0xa>(x);      // row_bcast15 -> rows 1,3
    x = dppmaxf_m<0x143, 0xc>(x);      // row_bcast31 -> lane63 full
    return x;
}
// 8-lane-group reduce (groups lane%8-aligned; all source lanes valid)
__device__ __forceinline__ float group8_max(float x) {
    x = fmaxf(x, movdpp_f<0xB1>(x));
    x = fmaxf(x, movdpp_f<0x4E>(x));
    x = fmaxf(x, movdpp_f<0x141>(x));
    return x;
}
__device__ __forceinline__ int group8_min_i(int x) {
    x = min(x, movdpp_i<0xB1>(x));
    x = min(x, movdpp_i<0x4E>(x));
    x = min(x, movdpp_i<0x141>(x));
    return x;
}

// ---------------------------------------------------------------------------
// Kernel 1: FPS, one block (512 thr, 8 waves) per batch. Bit-exact fp32
// (no FMA) distance chain. Thread t owns contiguous points [16t, 16t+16).
// In-loop: running fmin + fmax tree only. Argmax index resolved lazily:
// ballot(bd==bm) -> first candidate lane resolves its local j (1 wave pays).
// Contiguous layout => first candidate tid = smallest global index (np argmax
// first-occurrence, exact).
// ---------------------------------------------------------------------------
__global__ __launch_bounds__(512) void fps_kernel(const float4* __restrict__ events4,
                                                  int* __restrict__ down_idx,
                                                  float4* __restrict__ out_de) {
    extern __shared__ char smem[];
    float*  rv   = (float*)smem;                   // 8 floats: wave-max partials
    int*    wsl  = (int*)(smem + 32);              // 8 ints: per-wave winner idx
    int*    ssel = (int*)(smem + 64);              // 2048 ints
    float4* spt  = (float4*)(smem + 64 + 4 * M_PTS);

    const int b = blockIdx.x;
    const int tid = threadIdx.x;
    const int wave = tid >> 6;
    const int lane = tid & 63;
    const float4* ev = events4 + (size_t)b * N_PTS;

    for (int i = tid; i < N_PTS; i += 512) spt[i] = ev[i];
    if (tid == 0) ssel[0] = 0;
    __syncthreads();

    // 16 points/thread, packed in pairs
    v2f px[8], py[8], pz[8];
    float dist[16];
#pragma unroll
    for (int pp = 0; pp < 8; ++pp) {
        float4 f0 = spt[tid * 16 + 2 * pp];
        float4 f1 = spt[tid * 16 + 2 * pp + 1];
        px[pp] = (v2f){f0.x, f1.x};
        py[pp] = (v2f){f0.y, f1.y};
        pz[pp] = (v2f){f0.z, f1.z};
        dist[2 * pp] = 1e10f; dist[2 * pp + 1] = 1e10f;   // reference init
    }

    int last = 0;
    for (int i = 1; i < M_PTS; ++i) {
        float4 L = spt[last];                       // uniform ds_read_b128
        const float nlx = -L.x, nly = -L.y, nlz = -L.z;   // exact sign flips
        const v2f nx2 = (v2f){nlx, nlx};
        const v2f ny2 = (v2f){nly, nly};
        const v2f nz2 = (v2f){nlz, nlz};
#pragma unroll
        for (int pp = 0; pp < 8; ++pp) {
            v2f dx = pk_add(px[pp], nx2);           // == px - lx, exact
            v2f dy = pk_add(py[pp], ny2);
            v2f dz = pk_add(pz[pp], nz2);
            v2f s  = pk_add(pk_add(pk_mul(dx, dx), pk_mul(dy, dy)), pk_mul(dz, dz));
            dist[2 * pp]     = fminf(dist[2 * pp],     s.x);
            dist[2 * pp + 1] = fminf(dist[2 * pp + 1], s.y);
        }
        // pairwise fmax tree over 16 dists
        float m0 = fmaxf(dist[0], dist[1]),  m1 = fmaxf(dist[2], dist[3]);
        float m2 = fmaxf(dist[4], dist[5]),  m3 = fmaxf(dist[6], dist[7]);
        float m4 = fmaxf(dist[8], dist[9]),  m5 = fmaxf(dist[10], dist[11]);
        float m6 = fmaxf(dist[12], dist[13]), m7 = fmaxf(dist[14], dist[15]);
        m0 = fmaxf(m0, m1); m2 = fmaxf(m2, m3); m4 = fmaxf(m4, m5); m6 = fmaxf(m6, m7);
        float bd = fmaxf(fmaxf(m0, m2), fmaxf(m4, m6));

        // block max
        float wm = wave_max64(bd);
        if (lane == 63) rv[wave] = wm;
        __syncthreads();
        float bm = group8_max(rv[lane & 7]);        // uniform block max

        // lazy winner resolve: first candidate lane of each candidate wave
        bool cand = (bd == bm);
        unsigned long long mask = __ballot(cand);
        if (lane == 0) wsl[wave] = 0x7fffffff;      // same-wave DS order: init first
        if (mask != 0ULL) {
            int fl = (int)__ffsll((long long)mask) - 1;
            if (lane == fl) {
                int jm = 0;
#pragma unroll
                for (int j = 15; j >= 0; --j) if (dist[j] == bd) jm = j;  // smallest j
                wsl[wave] = tid * 16 + jm;
            }
        }
        __syncthreads();
        int winner = group8_min_i(wsl[lane & 7]);   // uniform: smallest candidate idx
        if (tid == 0) ssel[i] = winner;
        last = winner;
    }
    __syncthreads();

    for (int i = tid; i < M_PTS; i += 512) {
        int s = ssel[i];
        down_idx[b * M_PTS + i] = s;
        out_de[(size_t)b * M_PTS + i] = spt[s];
    }
}

// ---------------------------------------------------------------------------
// Kernel 2: 16-NN, divergence-free threshold algorithm (unchanged from R7).
// ---------------------------------------------------------------------------
__global__ __launch_bounds__(256) void knn_kernel(const float4* __restrict__ events4,
                                                  const int* __restrict__ down_idx,
                                                  int* __restrict__ knn_idx) {
    extern __shared__ char smem[];
    float* sx   = (float*)smem;
    float* sy   = sx + N_PTS;
    float* sz   = sy + N_PTS;
    float* cd   = sz + N_PTS;
    int*   ci   = (int*)(cd + 32 * KCAP);
    int*   scnt = (int*)(ci + 32 * KCAP);

    const int b    = blockIdx.x >> 6;
    const int qg   = blockIdx.x & 63;
    const int tid  = threadIdx.x;
    const int ql   = tid >> 3;
    const int part = tid & 7;

    const float4* ev = events4 + (size_t)b * N_PTS;
    for (int i = tid; i < N_PTS; i += 256) {
        float4 e = ev[i];
        sx[i] = e.x; sy[i] = e.y; sz[i] = e.z;
    }
    if (tid < 32) scnt[tid] = 0;
    __syncthreads();

    const int q  = qg * 32 + ql;
    const int qi = down_idx[b * M_PTS + q];
    const float qx = sx[qi], qy = sy[qi], qz = sz[qi];

    float m1 = 1e30f, m2 = 1e30f;
    for (int i = 0; i < N_PTS / 8; ++i) {
        const int p = i * 8 + part;
        float d = sqdist_rn(sx[p], sy[p], sz[p], qx, qy, qz);
        float lo = fminf(m1, d);
        m2 = fminf(m2, fmaxf(m1, d));
        m1 = lo;
    }
    const float T = group8_max(m2);

    for (int i = 0; i < N_PTS / 8; ++i) {
        const int p = i * 8 + part;
        float d = sqdist_rn(sx[p], sy[p], sz[p], qx, qy, qz);
        if (d <= T) {
            int pos = atomicAdd(&scnt[ql], 1);
            if (pos < KCAP) { cd[ql * KCAP + pos] = d; ci[ql * KCAP + pos] = p; }
        }
    }
    __syncthreads();

    if (part == 0) {
        float nd[16]; int ni[16];
#pragma unroll
        for (int j = 0; j < 16; ++j) { nd[j] = 1e30f; ni[j] = 0x7fffffff; }
        float wmax = 1e30f; int widx = 0x7fffffff; int wslot = 0;
        const int n = scnt[ql];
        const int lim = (n <= KCAP) ? n : 0;
        for (int t = 0; t < lim; ++t) {
            float d = cd[ql * KCAP + t];
            int   p = ci[ql * KCAP + t];
            if (d < wmax || (d == wmax && p < widx)) {
#pragma unroll
                for (int j = 0; j < 16; ++j) if (j == wslot) { nd[j] = d; ni[j] = p; }
                float m_ = -1.0f; int mix_ = -1; int ms_ = 0;
#pragma unroll
                for (int j = 0; j < 16; ++j)
                    if (nd[j] > m_ || (nd[j] == m_ && ni[j] > mix_)) { m_ = nd[j]; mix_ = ni[j]; ms_ = j; }
                wmax = m_; widx = mix_; wslot = ms_;
            }
        }
        if (n > KCAP) {
            for (int p = 0; p < N_PTS; ++p) {
                float d = sqdist_rn(sx[p], sy[p], sz[p], qx, qy, qz);
                if (d < wmax || (d == wmax && p < widx)) {
#pragma unroll
                    for (int j = 0; j < 16; ++j) if (j == wslot) { nd[j] = d; ni[j] = p; }
                    float m_ = -1.0f; int mix_ = -1; int ms_ = 0;
#pragma unroll
                    for (int j = 0; j < 16; ++j)
                        if (nd[j] > m_ || (nd[j] == m_ && ni[j] > mix_)) { m_ = nd[j]; mix_ = ni[j]; ms_ = j; }
                    wmax = m_; widx = mix_; wslot = ms_;
                }
            }
        }
        int* out = knn_idx + ((size_t)(b * M_PTS + q)) * K_NN;
#pragma unroll
        for (int j = 0; j < 16; ++j) out[j] = ni[j];
    }
}

// ---------------------------------------------------------------------------
// Kernel 3: gather + per-query (16x68)@(68x128) matmul + bias (unchanged).
// ---------------------------------------------------------------------------
__global__ __launch_bounds__(256) void gmm_kernel(const float* __restrict__ events,
                                                  const float* __restrict__ features,
                                                  const float* __restrict__ W,
                                                  const float* __restrict__ bias,
                                                  const int* __restrict__ knn_idx,
                                                  const float* __restrict__ de,
                                                  float* __restrict__ hmax_g,
                                                  float* __restrict__ hmin_g,
                                                  float* __restrict__ gsum,
                                                  float* __restrict__ gsq) {
    __shared__ __align__(16) float sg[16 * G_CH];
    __shared__ float scomb[2 * OUT_CH];

    const int b   = blockIdx.x >> 7;
    const int qg  = blockIdx.x & 127;
    const int tid = threadIdx.x;
    const int d   = tid & 127;
    const int kh  = tid >> 7;

    float w[G_CH];
#pragma unroll
    for (int c = 0; c < G_CH; ++c) w[c] = W[c * OUT_CH + d];
    const float breg = bias[d];

    float ssum = 0.f, ssq = 0.f;
    const float4* sg4 = (const float4*)sg;

    for (int qq = 0; qq < 16; ++qq) {
        const int q = qg * 16 + qq;
        const int base = b * M_PTS + q;
        for (int j = tid; j < 16 * G_CH; j += 256) {
            int k = j / G_CH;
            int c = j - k * G_CH;
            int nb = knn_idx[base * K_NN + k];
            float v;
            if (c < 4) v = events[((size_t)(b * N_PTS + nb)) * 4 + c] - de[(size_t)base * 4 + c];
            else       v = features[((size_t)(b * N_PTS + nb)) * IN_CH + (c - 4)];
            sg[j] = v;
        }
        __syncthreads();

        float hmax = -1e30f, hmin = 1e30f;
#pragma unroll
        for (int k2 = 0; k2 < 8; ++k2) {
            const int k = kh * 8 + k2;
            float acc = breg;
#pragma unroll
            for (int c4 = 0; c4 < 17; ++c4) {
                float4 g = sg4[k * 17 + c4];
                acc = fmaf(g.x, w[4 * c4 + 0], acc);
                acc = fmaf(g.y, w[4 * c4 + 1], acc);
                acc = fmaf(g.z, w[4 * c4 + 2], acc);
                acc = fmaf(g.w, w[4 * c4 + 3], acc);
            }
            hmax = fmaxf(hmax, acc);
            hmin = fminf(hmin, acc);
            ssum += acc;
            ssq = fmaf(acc, acc, ssq);
        }
        if (kh == 1) { scomb[d] = hmax; scomb[OUT_CH + d] = hmin; }
        __syncthreads();
        if (kh == 0) {
            hmax = fmaxf(hmax, scomb[d]);
            hmin = fminf(hmin, scomb[OUT_CH + d]);
            hmax_g[(size_t)base * OUT_CH + d] = hmax;
            hmin_g[(size_t)base * OUT_CH + d] = hmin;
        }
        __syncthreads();
    }
    if (kh == 1) { scomb[d] = ssum; scomb[OUT_CH + d] = ssq; }
    __syncthreads();
    if (kh == 0) {
        atomicAdd(&gsum[d], ssum + scomb[d]);
        atomicAdd(&gsq[d],  ssq  + scomb[OUT_CH + d]);
    }
}

// ---------------------------------------------------------------------------
// Kernel 4: BN affine + relu + max-over-k via hmax/hmin (unchanged).
// ---------------------------------------------------------------------------
__global__ __launch_bounds__(256) void fin_kernel(const float* __restrict__ hmax_g,
                                                  const float* __restrict__ hmin_g,
                                                  const float* __restrict__ gsum,
                                                  const float* __restrict__ gsq,
                                                  const float* __restrict__ gamma,
                                                  const float* __restrict__ beta,
                                                  float* __restrict__ out) {
    const size_t e = (size_t)blockIdx.x * 256 + threadIdx.x;
    const int d = (int)(e & 127);
    const float inv_cnt = 1.0f / 131072.0f;
    float mu  = gsum[d] * inv_cnt;
    float var = gsq[d] * inv_cnt - mu * mu;
    float a   = gamma[d] * rsqrtf(var + 1e-5f);
    float sh  = fmaf(-mu, a, beta[d]);
    float hv  = (a >= 0.f) ? hmax_g[e] : hmin_g[e];
    float r   = fmaf(a, hv, sh);
    out[32768 + e] = r > 0.f ? r : 0.f;
}

// ---------------------------------------------------------------------------
extern "C" void kernel_launch(void* const* d_in, const int* in_sizes, int n_in,
                              void* d_out, int out_size, void* d_ws, size_t ws_size,
                              hipStream_t stream) {
    const float* events   = (const float*)d_in[0];
    const float* features = (const float*)d_in[1];
    const float* W        = (const float*)d_in[2];
    const float* bias     = (const float*)d_in[3];
    const float* gamma    = (const float*)d_in[4];
    const float* beta     = (const float*)d_in[5];
    float* out = (float*)d_out;
    char* ws = (char*)d_ws;

    int*   down_idx = (int*)ws;                          // 32768 B
    int*   knn_idx  = (int*)(ws + 32768);                // 524288 B
    float* gsum     = (float*)(ws + 32768 + 524288);     // 512 B
    float* gsq      = gsum + OUT_CH;                     // 512 B
    float* hmaxg    = (float*)(ws + 558080);             // 4 MB
    float* hming    = hmaxg + (size_t)4 * M_PTS * OUT_CH;// 4 MB

    (void)hipMemsetAsync(gsum, 0, 2 * OUT_CH * sizeof(float), stream);

    const size_t fps_lds = 64 + 4 * M_PTS + (size_t)N_PTS * sizeof(float4); // 139328
    fps_kernel<<<4, 512, fps_lds, stream>>>((const float4*)events, down_idx, (float4*)out);

    const size_t knn_lds = (size_t)3 * N_PTS * sizeof(float)
                         + (size_t)32 * KCAP * 8 + 128;                      // 131200
    knn_kernel<<<256, 256, knn_lds, stream>>>((const float4*)events, down_idx, knn_idx);

    gmm_kernel<<<512, 256, 0, stream>>>(events, features, W, bias, knn_idx, out,
                                        hmaxg, hming, gsum, gsq);

    fin_kernel<<<4096, 256, 0, stream>>>(hmaxg, hming, gsum, gsq, gamma, beta, out);
}